// Round 12
// baseline (317.667 us; speedup 1.0000x reference)
//
#include <hip/hip_runtime.h>
#include <hip/hip_bf16.h>
#include <cstdint>

typedef __attribute__((ext_vector_type(4))) float f32x4;
typedef _Float16 f16x8 __attribute__((ext_vector_type(8)));

#define BN_EPS 1e-5f

// ---------------- fp32 -> fp16 cast (only W, 4 MB) ----------------
__global__ __launch_bounds__(256)
void cast_f32_f16(const float* __restrict__ src, _Float16* __restrict__ dst, int n8) {
    int i = blockIdx.x * blockDim.x + threadIdx.x;
    if (i >= n8) return;
    const float4* s4 = (const float4*)src;
    float4 a = s4[2 * (size_t)i];
    float4 b = s4[2 * (size_t)i + 1];
    f16x8 h;
    h[0] = (_Float16)a.x; h[1] = (_Float16)a.y; h[2] = (_Float16)a.z; h[3] = (_Float16)a.w;
    h[4] = (_Float16)b.x; h[5] = (_Float16)b.y; h[6] = (_Float16)b.z; h[7] = (_Float16)b.w;
    *(f16x8*)(dst + 8 * (size_t)i) = h;
}

// async global->LDS, 16B per lane, wave-uniform LDS base
__device__ __forceinline__ void async16(const char* g, char* l) {
    __builtin_amdgcn_global_load_lds(
        (const __attribute__((address_space(1))) unsigned int*)(uintptr_t)g,
        (__attribute__((address_space(3))) unsigned int*)(uintptr_t)l,
        16, 0, 0);
}

// ====== r11 + A LDS layout fix: A fp32 stored as TWO k-half buffers [256][16] fp32 ======
// 64B rows (bank = 16*(row&1) + 4*slot -> row-parity split), i.e. byte-identical geometry
// to the PROVEN 0-conflict B path (r3-r9), swizzle slot ^= (row>>1)&3 on both sides.
// r11's [256][32] fp32 layout had 128B rows = 32-bank stride -> every row bank-aligned ->
// 1.678e7 conflicts. Per tile: A half h holds k 16h..16h+15; fragment (fr,kg) reads half
// kg>>1, slots (kg&1)*2 and +1, cvt fp32->f16 in regs (hides under MFMA).
// Staging/ledger identical to r11: 6 issues/tile (A x4, B x2), depth-2, vmcnt(6), tail 0.

#define ABUF(t) (lds + ((t) % 3) * 32768)
#define BBUF(t) (lds + 98304 + ((t) % 3) * 16384)

__device__ __forceinline__ void stageTile(int t, char* lds,
                                          const char* aT, const char* bT,
                                          int wid, size_t K4, size_t K2) {
    char* dA = ABUF(t) + wid * 1024;
    const char* sA = aT + (size_t)t * 128;
    async16(sA,                         dA);                 // half0, rows 0-127
    async16(sA + (size_t)128 * K4,      dA + 8192);          // half0, rows 128-255
    async16(sA + 64,                    dA + 16384);         // half1, rows 0-127
    async16(sA + (size_t)128 * K4 + 64, dA + 24576);         // half1, rows 128-255
    char* dB = BBUF(t) + wid * 1024;
    const char* sB = bT + (size_t)t * 64;
    async16(sB, dB);
    async16(sB + (size_t)128 * K2, dB + 8192);
}

template<int WAITSEL, bool STAGE, bool BAR>
__device__ __forceinline__ void ktile(
    int kt, char* lds, const char* aT, const char* bT,
    int wid, int ah, int as0, int as1, int boff, size_t K4, size_t K2, f32x4 (&acc)[8][4])
{
    if (STAGE) stageTile(kt + 2, lds, aT, bT, wid, K4, K2);
    const char* ab = ABUF(kt);
    const char* bb = BBUF(kt);
    f16x8 a[8], b[4];
    #pragma unroll
    for (int n = 0; n < 4; ++n) b[n] = *(const f16x8*)(bb + boff + n * 1024);
    #pragma unroll
    for (int m = 0; m < 8; ++m) {
        f32x4 lo = *(const f32x4*)(ab + ah + as0 + m * 1024);
        f32x4 hi = *(const f32x4*)(ab + ah + as1 + m * 1024);
        f16x8 h;
        h[0] = (_Float16)lo[0]; h[1] = (_Float16)lo[1];
        h[2] = (_Float16)lo[2]; h[3] = (_Float16)lo[3];
        h[4] = (_Float16)hi[0]; h[5] = (_Float16)hi[1];
        h[6] = (_Float16)hi[2]; h[7] = (_Float16)hi[3];
        a[m] = h;
    }
    __builtin_amdgcn_s_setprio(1);
    #pragma unroll
    for (int m = 0; m < 8; ++m)
        #pragma unroll
        for (int n = 0; n < 4; ++n)
            acc[m][n] = __builtin_amdgcn_mfma_f32_16x16x32_f16(a[m], b[n], acc[m][n], 0, 0, 0);
    __builtin_amdgcn_s_setprio(0);
    if (WAITSEL == 2)      { asm volatile("s_waitcnt vmcnt(6)" ::: "memory"); }
    else if (WAITSEL == 1) { asm volatile("s_waitcnt vmcnt(0)" ::: "memory"); }
    if (BAR) __builtin_amdgcn_s_barrier();
}

__global__ __launch_bounds__(512, 2)
void gemm_gbn_kernel(const float* __restrict__ Af,
                     const _Float16* __restrict__ Bw,
                     const float* __restrict__ priors,
                     const float* __restrict__ gamma,
                     const float* __restrict__ beta,
                     float* __restrict__ Z,
                     int M, int N, int K)
{
    __shared__ __align__(16) char lds[147456];   // 144 KB

    const int tid  = threadIdx.x;
    const int lane = tid & 63;
    const int wid  = tid >> 6;     // 0..7
    const int wr   = wid >> 2;     // 0..1  (128-row half == one virtual batch)
    const int wc   = wid & 3;      // 0..3  (64-col slice)
    const int fr   = lane & 15;
    const int kg   = lane >> 4;
    const size_t K4 = (size_t)K * 4;
    const size_t K2 = (size_t)K * 2;

    // XCD-aware bijective swizzle (512 blocks, %8==0)
    const int bid = blockIdx.x;
    const int swz = (bid & 7) * 64 + (bid >> 3);
    const int row0 = (swz >> 2) * 256;
    const int col0 = (swz & 3) * 256;

    // A staging source: fp32, row = tid>>2 within 128-row chunk; 4 slots of 16B per 64B
    // k-half row segment; pre-permuted slot (involution matching read swizzle)
    const int aperm = ((tid & 3) ^ ((tid >> 3) & 3)) * 16;
    const char* aT = (const char*)Af + (size_t)(row0 + (tid >> 2)) * K4 + aperm;

    // B staging source: f16 (identical pattern)
    const int bperm = ((tid & 3) ^ ((tid >> 3) & 3)) * 16;
    const char* bT = (const char*)Bw + (size_t)(col0 + (tid >> 2)) * K2 + bperm;

    // A fragment read offsets (half-buffer [256][16] fp32, 64B rows, B-style swizzle):
    // half = kg>>1 (16KB), logical slots (kg&1)*2 and +1 within row (wr*128 + m*16 + fr)
    const int ah = (kg >> 1) * 16384;
    int as0 = (wr * 128 + fr) * 64 + (kg & 1) * 32;
    int as1 = as0 + 16;
    as0 ^= ((as0 >> 7) & 3) << 4;
    as1 ^= ((as1 >> 7) & 3) << 4;

    // B fragment read base ([256][32] f16, 64B rows), proven 0-conflict swizzle
    int boff = (wc * 64 + fr) * 64 + kg * 16;
    boff ^= ((boff >> 7) & 3) << 4;

    f32x4 acc[8][4];
    #pragma unroll
    for (int m = 0; m < 8; ++m)
        #pragma unroll
        for (int n = 0; n < 4; ++n)
            acc[m][n] = (f32x4)0.0f;

    // prologue: stage tiles 0,1; vmcnt(6) -> tile 0 resident, tile 1 in flight
    stageTile(0, lds, aT, bT, wid, K4, K2);
    stageTile(1, lds, aT, bT, wid, K4, K2);
    asm volatile("s_waitcnt vmcnt(6)" ::: "memory");
    __builtin_amdgcn_s_barrier();

    const int nt = K >> 5;                 // 64 K-tiles of 32
    for (int kt = 0; kt < nt - 2; ++kt)
        ktile<2, true,  true >(kt, lds, aT, bT, wid, ah, as0, as1, boff, K4, K2, acc);
    ktile<1, false, true >(nt - 2, lds, aT, bT, wid, ah, as0, as1, boff, K4, K2, acc);
    ktile<0, false, false>(nt - 1, lds, aT, bT, wid, ah, as0, as1, boff, K4, K2, acc);

    // ---- fused Ghost BatchNorm + priors epilogue (wave-local: wr half = one VBS) ----
    #pragma unroll
    for (int n = 0; n < 4; ++n) {
        float s1 = 0.f, s2 = 0.f;
        #pragma unroll
        for (int m = 0; m < 8; ++m)
            #pragma unroll
            for (int j = 0; j < 4; ++j) {
                float v = acc[m][n][j];
                s1 += v; s2 += v * v;
            }
        s1 += __shfl_xor(s1, 16); s2 += __shfl_xor(s2, 16);
        s1 += __shfl_xor(s1, 32); s2 += __shfl_xor(s2, 32);
        float mean = s1 * (1.f / 128.f);
        float var  = s2 * (1.f / 128.f) - mean * mean;
        float rstd = rsqrtf(var + BN_EPS);
        const int c = col0 + wc * 64 + n * 16 + fr;
        float g = gamma[c] * rstd;
        float b = beta[c] - mean * g;
        #pragma unroll
        for (int m = 0; m < 8; ++m)
            #pragma unroll
            for (int j = 0; j < 4; ++j) {
                int r = row0 + wr * 128 + m * 16 + kg * 4 + j;
                size_t off = (size_t)r * N + c;
                Z[off] = (acc[m][n][j] * g + b) * priors[off];
            }
    }
}

// ---------------- sparsemax: one wave per row of 1024, exact Michelot projection ----------------
__device__ __forceinline__ float waveSum(float v) {
    #pragma unroll
    for (int off = 32; off > 0; off >>= 1) v += __shfl_xor(v, off);
    return v;
}

__global__ __launch_bounds__(256)
void sparsemax_kernel(float* __restrict__ Z) {
    const int lane = threadIdx.x & 63;
    const int wid  = threadIdx.x >> 6;
    const size_t row = (size_t)blockIdx.x * 4 + wid;
    float4* zr4 = (float4*)(Z + row * 1024);

    float p[16];
    #pragma unroll
    for (int j = 0; j < 4; ++j) {
        float4 t = zr4[lane * 4 + j];
        p[4 * j + 0] = t.x; p[4 * j + 1] = t.y; p[4 * j + 2] = t.z; p[4 * j + 3] = t.w;
    }

    float s = 0.f;
    #pragma unroll
    for (int i = 0; i < 16; ++i) s += p[i];
    s = waveSum(s);

    float kc  = 1024.f;
    float tau = (s - 1.f) * (1.f / 1024.f);
    for (int it = 0; it < 64; ++it) {
        float s2 = 0.f, c2 = 0.f;
        #pragma unroll
        for (int i = 0; i < 16; ++i) {
            if (p[i] > tau) { s2 += p[i]; c2 += 1.f; }
        }
        s2 = waveSum(s2); c2 = waveSum(c2);
        if (c2 == kc) break;        // support stable -> tau exact
        kc = c2;
        tau = (s2 - 1.f) / c2;
    }

    #pragma unroll
    for (int j = 0; j < 4; ++j) {
        float4 o;
        o.x = fmaxf(p[4 * j + 0] - tau, 0.f);
        o.y = fmaxf(p[4 * j + 1] - tau, 0.f);
        o.z = fmaxf(p[4 * j + 2] - tau, 0.f);
        o.w = fmaxf(p[4 * j + 3] - tau, 0.f);
        zr4[lane * 4 + j] = o;
    }
}

extern "C" void kernel_launch(void* const* d_in, const int* in_sizes, int n_in,
                              void* d_out, int out_size, void* d_ws, size_t ws_size,
                              hipStream_t stream)
{
    const float* priors = (const float*)d_in[0];
    const float* feat   = (const float*)d_in[1];
    const float* W      = (const float*)d_in[2];
    const float* gamma  = (const float*)d_in[3];
    const float* beta   = (const float*)d_in[4];
    float* out = (float*)d_out;

    const int Nf = in_sizes[3];              // 1024
    const int Kf = in_sizes[2] / Nf;         // 2048
    const int Mr = in_sizes[1] / Kf;         // 32768

    _Float16* Wh = (_Float16*)d_ws;          // N*K*2 = 4 MB (only W is pre-cast)

    {
        int n8 = Nf * (Kf / 8);
        cast_f32_f16<<<(n8 + 255) / 256, 256, 0, stream>>>(W, Wh, n8);
    }

    int nblk = (Mr / 256) * (Nf / 256);      // 512, divisible by 8
    gemm_gbn_kernel<<<nblk, 512, 0, stream>>>(feat, Wh, priors, gamma, beta, out, Mr, Nf, Kf);

    sparsemax_kernel<<<Mr / 4, 256, 0, stream>>>(out);
}